// Round 13
// baseline (47.447 us; speedup 1.0000x reference)
//
#include <hip/hip_runtime.h>
#include <hip/hip_bf16.h>

#define B_TOTAL 1000000
// one wave (64 threads) per block: no barriers, no inter-wave coupling
#define NBLK64 ((B_TOTAL + 63) / 64)

// float4 with 4-byte alignment: element base is b*84 B, only 4-B aligned.
typedef float f4u __attribute__((ext_vector_type(4), aligned(4)));

// upper-tri packed index for (i,j), i<=j, of a 6x6
__device__ __forceinline__ constexpr int up_idx(int i, int j) {
    return i * 6 - i * (i - 1) / 2 + (j - i);
}

__device__ __forceinline__ void load21(const float* __restrict__ src, float* dst) {
#pragma unroll
    for (int q = 0; q < 5; ++q) {
        f4u v = *reinterpret_cast<const f4u*>(src + 4 * q);
        dst[4 * q + 0] = v[0]; dst[4 * q + 1] = v[1];
        dst[4 * q + 2] = v[2]; dst[4 * q + 3] = v[3];
    }
    dst[20] = src[20];
}

// Cholesky (lower) of symmetric 6x6 given packed upper-tri v[21], diag += 1e-5.
// Uses hw-approx v_rsq_f32 (~1 ULP): d = s*rsq(s), 1/d = rsq(s). Tolerance is 2%.
__device__ __forceinline__ void chol6(const float* v, float L[6][6], float dinv[6]) {
#pragma unroll
    for (int j = 0; j < 6; ++j) {
        float s = v[up_idx(j, j)] + 1e-5f;
#pragma unroll
        for (int k = 0; k < 6; ++k)
            if (k < j) s -= L[j][k] * L[j][k];
        float r = __builtin_amdgcn_rsqf(s);
        L[j][j] = s * r;  // sqrt(s)
        dinv[j] = r;
#pragma unroll
        for (int i = 0; i < 6; ++i)
            if (i > j) {
                float a = v[up_idx(j, i)];
#pragma unroll
                for (int k = 0; k < 6; ++k)
                    if (k < j) a -= L[i][k] * L[j][k];
                L[i][j] = a * r;
            }
    }
}

// full per-element loss: huber/21 + KL
__device__ __forceinline__ float element_loss(const float* t, const float* p) {
    float hs = 0.0f;
#pragma unroll
    for (int k = 0; k < 21; ++k) {
        float d = p[k] - t[k];
        float ad = fabsf(d);
        hs += (ad < 1.0f) ? 0.5f * d * d : ad - 0.5f;
    }

    float Lt[6][6], Lp[6][6], dti[6], dpi[6];
    chol6(t, Lt, dti);
    chol6(p, Lp, dpi);

    // M = Lt^{-1} Lp (forward substitution per column), tr = sum(M*M)
    float tr = 0.0f;
#pragma unroll
    for (int c = 0; c < 6; ++c) {
        float m[6];
#pragma unroll
        for (int r = 0; r < 6; ++r)
            if (r >= c) {
                float s = Lp[r][c];
#pragma unroll
                for (int k = 0; k < 6; ++k)
                    if (k >= c && k < r) s -= Lt[r][k] * m[k];
                m[r] = s * dti[r];
                tr += m[r] * m[r];
            }
    }

    float ratio = 1.0f;
#pragma unroll
    for (int i = 0; i < 6; ++i) ratio *= Lt[i][i] * dpi[i];
    // ln(x) = log2(x) * ln(2); v_log_f32 is hw log2
    float kl = 0.5f * (tr - 6.0f) + 0.69314718056f * __builtin_amdgcn_logf(ratio);

    return kl + hs * (1.0f / 21.0f);
}

__global__ void __launch_bounds__(64) kl_huber_kernel(const float* __restrict__ target,
                                                      const float* __restrict__ pred,
                                                      double* __restrict__ partial) {
    const int tid = threadIdx.x;
    const long b = (long)blockIdx.x * 64 + tid;
    float contrib = 0.0f;
    if (b < B_TOTAL) {
        float t[21], p[21];
        load21(target + b * 21, t);
        load21(pred + b * 21, p);
        contrib = element_loss(t, p);
    }

    // wave (64-lane) reduce; block == one wave, so no barrier needed anywhere
#pragma unroll
    for (int off = 32; off > 0; off >>= 1) contrib += __shfl_down(contrib, off);

    if (tid == 0) partial[blockIdx.x] = (double)contrib;
}

__global__ void __launch_bounds__(256) reduce_kernel(const double* __restrict__ partial,
                                                     float* __restrict__ out) {
    double s = 0.0;
    for (int i = threadIdx.x; i < NBLK64; i += 256) s += partial[i];
#pragma unroll
    for (int off = 32; off > 0; off >>= 1) s += __shfl_down(s, off);

    __shared__ double wsum[4];
    int lane = threadIdx.x & 63;
    int wid = threadIdx.x >> 6;
    if (lane == 0) wsum[wid] = s;
    __syncthreads();
    if (threadIdx.x == 0) {
        double total = wsum[0] + wsum[1] + wsum[2] + wsum[3];
        out[0] = (float)(total / (double)B_TOTAL);
    }
}

extern "C" void kernel_launch(void* const* d_in, const int* in_sizes, int n_in,
                              void* d_out, int out_size, void* d_ws, size_t ws_size,
                              hipStream_t stream) {
    const float* target = (const float*)d_in[0];
    const float* pred = (const float*)d_in[1];
    double* partial = (double*)d_ws;  // NBLK64 doubles = 125 KB

    kl_huber_kernel<<<NBLK64, 64, 0, stream>>>(target, pred, partial);
    reduce_kernel<<<1, 256, 0, stream>>>(partial, (float*)d_out);
}

// Round 15
// 34.443 us; speedup vs baseline: 1.3775x; 1.3775x over previous
//
#include <hip/hip_runtime.h>
#include <hip/hip_bf16.h>

#define B_TOTAL 1000000
// 2 elements per thread: each block covers 512 elements
#define NBLK2 ((B_TOTAL + 511) / 512)

// float4 with 4-byte alignment: element base is b*84 B, only 4-B aligned.
typedef float f4u __attribute__((ext_vector_type(4), aligned(4)));

// upper-tri packed index for (i,j), i<=j, of a 6x6
__device__ __forceinline__ constexpr int up_idx(int i, int j) {
    return i * 6 - i * (i - 1) / 2 + (j - i);
}

__device__ __forceinline__ void load21(const float* __restrict__ src, float* dst) {
#pragma unroll
    for (int q = 0; q < 5; ++q) {
        f4u v = *reinterpret_cast<const f4u*>(src + 4 * q);
        dst[4 * q + 0] = v[0]; dst[4 * q + 1] = v[1];
        dst[4 * q + 2] = v[2]; dst[4 * q + 3] = v[3];
    }
    dst[20] = src[20];
}

// Cholesky (lower) of symmetric 6x6 given packed upper-tri v[21], diag += 1e-5.
// Uses hw-approx v_rsq_f32 (~1 ULP): d = s*rsq(s), 1/d = rsq(s). Tolerance is 2%.
__device__ __forceinline__ void chol6(const float* v, float L[6][6], float dinv[6]) {
#pragma unroll
    for (int j = 0; j < 6; ++j) {
        float s = v[up_idx(j, j)] + 1e-5f;
#pragma unroll
        for (int k = 0; k < 6; ++k)
            if (k < j) s -= L[j][k] * L[j][k];
        float r = __builtin_amdgcn_rsqf(s);
        L[j][j] = s * r;  // sqrt(s)
        dinv[j] = r;
#pragma unroll
        for (int i = 0; i < 6; ++i)
            if (i > j) {
                float a = v[up_idx(j, i)];
#pragma unroll
                for (int k = 0; k < 6; ++k)
                    if (k < j) a -= L[i][k] * L[j][k];
                L[i][j] = a * r;
            }
    }
}

// full per-element loss: huber/21 + KL
__device__ __forceinline__ float element_loss(const float* t, const float* p) {
    float hs = 0.0f;
#pragma unroll
    for (int k = 0; k < 21; ++k) {
        float d = p[k] - t[k];
        float ad = fabsf(d);
        hs += (ad < 1.0f) ? 0.5f * d * d : ad - 0.5f;
    }

    float Lt[6][6], Lp[6][6], dti[6], dpi[6];
    chol6(t, Lt, dti);
    chol6(p, Lp, dpi);

    // M = Lt^{-1} Lp (forward substitution per column), tr = sum(M*M)
    float tr = 0.0f;
#pragma unroll
    for (int c = 0; c < 6; ++c) {
        float m[6];
#pragma unroll
        for (int r = 0; r < 6; ++r)
            if (r >= c) {
                float s = Lp[r][c];
#pragma unroll
                for (int k = 0; k < 6; ++k)
                    if (k >= c && k < r) s -= Lt[r][k] * m[k];
                m[r] = s * dti[r];
                tr += m[r] * m[r];
            }
    }

    float ratio = 1.0f;
#pragma unroll
    for (int i = 0; i < 6; ++i) ratio *= Lt[i][i] * dpi[i];
    // ln(x) = log2(x) * ln(2); v_log_f32 is hw log2
    float kl = 0.5f * (tr - 6.0f) + 0.69314718056f * __builtin_amdgcn_logf(ratio);

    return kl + hs * (1.0f / 21.0f);
}

__global__ void __launch_bounds__(256) kl_huber_kernel(const float* __restrict__ target,
                                                       const float* __restrict__ pred,
                                                       double* __restrict__ partial) {
    const int tid = threadIdx.x;
    const long base = (long)blockIdx.x * 512;
    const long b0 = base + tid;
    const long b1 = base + 256 + tid;
    const bool valid0 = b0 < B_TOTAL;
    const bool valid1 = b1 < B_TOTAL;

    // issue ALL loads for both elements up front (MLP=24), compute after.
    // elem0's compute overlaps elem1's load latency.
    float t0[21], p0[21], t1[21], p1[21];
    if (valid0) {
        load21(target + b0 * 21, t0);
        load21(pred + b0 * 21, p0);
    }
    if (valid1) {
        load21(target + b1 * 21, t1);
        load21(pred + b1 * 21, p1);
    }

    float contrib = 0.0f;
    if (valid0) contrib += element_loss(t0, p0);
    if (valid1) contrib += element_loss(t1, p1);

    // wave (64-lane) reduce
#pragma unroll
    for (int off = 32; off > 0; off >>= 1) contrib += __shfl_down(contrib, off);

    __shared__ float wsum[4];
    int lane = tid & 63;
    int wid = tid >> 6;
    if (lane == 0) wsum[wid] = contrib;
    __syncthreads();
    if (tid == 0) {
        // one plain store per block: no atomic contention
        partial[blockIdx.x] = (double)(wsum[0] + wsum[1] + wsum[2] + wsum[3]);
    }
}

__global__ void __launch_bounds__(256) reduce_kernel(const double* __restrict__ partial,
                                                     float* __restrict__ out) {
    double s = 0.0;
    for (int i = threadIdx.x; i < NBLK2; i += 256) s += partial[i];
#pragma unroll
    for (int off = 32; off > 0; off >>= 1) s += __shfl_down(s, off);

    __shared__ double wsum[4];
    int lane = threadIdx.x & 63;
    int wid = threadIdx.x >> 6;
    if (lane == 0) wsum[wid] = s;
    __syncthreads();
    if (threadIdx.x == 0) {
        double total = wsum[0] + wsum[1] + wsum[2] + wsum[3];
        out[0] = (float)(total / (double)B_TOTAL);
    }
}

extern "C" void kernel_launch(void* const* d_in, const int* in_sizes, int n_in,
                              void* d_out, int out_size, void* d_ws, size_t ws_size,
                              hipStream_t stream) {
    const float* target = (const float*)d_in[0];
    const float* pred = (const float*)d_in[1];
    double* partial = (double*)d_ws;  // NBLK2 doubles = 15632 B

    kl_huber_kernel<<<NBLK2, 256, 0, stream>>>(target, pred, partial);
    reduce_kernel<<<1, 256, 0, stream>>>(partial, (float*)d_out);
}